// Round 2
// baseline (190.684 us; speedup 1.0000x reference)
//
#include <hip/hip_runtime.h>
#include <math.h>

// Problem constants (from reference setup_inputs)
constexpr int B = 64;
constexpr int T = 1024;
constexpr int C = 128;
constexpr int L = 256;
constexpr int S = 2 * L + 1;     // 513 extended states
constexpr int TRB = 2048;        // transpose blocks (blockIdx >= B)

template <int N> struct IC { static constexpr int value = N; };

// shfl_up by 1 lane as pure VALU DPP (wave_shr:1), bound_ctrl=1 so lane 0
// reads 0 (the CTC halo boundary) WITHOUT a v_mov-zero of the old operand.
// R8: the old update_dpp(old=0, bc=false) form cost an extra v_mov per call
// (~20 VALU/group).
__device__ __forceinline__ float shr1(float x) {
#if __has_builtin(__builtin_amdgcn_mov_dpp)
    return __int_as_float(__builtin_amdgcn_mov_dpp(
        __float_as_int(x), 0x138 /*WAVE_SHR1*/, 0xf, 0xf, true));
#else
    return __int_as_float(__builtin_amdgcn_update_dpp(
        0, __float_as_int(x), 0x138, 0xf, 0xf, true));
#endif
}

// One DPP max-combine stage. bound_ctrl=1: source-less lanes read 0, which
// is harmless for a max of non-negative alphas. Single v_mov_b32_dpp + fmax.
template <int CTRL>
__device__ __forceinline__ float maxdpp(float x) {
#if __has_builtin(__builtin_amdgcn_mov_dpp)
    float t = __int_as_float(__builtin_amdgcn_mov_dpp(
        __float_as_int(x), CTRL, 0xf, 0xf, true));
#else
    float t = __int_as_float(__builtin_amdgcn_update_dpp(
        0, __float_as_int(x), CTRL, 0xf, 0xf, true));
#endif
    return fmaxf(x, t);
}

// Wave64 max-reduce -> wave-uniform value (readlane 63).
__device__ __forceinline__ float wave_max_dpp(float x) {
    x = maxdpp<0x111>(x);   // row_shr:1
    x = maxdpp<0x112>(x);   // row_shr:2
    x = maxdpp<0x114>(x);   // row_shr:4
    x = maxdpp<0x118>(x);   // row_shr:8
    x = maxdpp<0x142>(x);   // row_bcast:15
    x = maxdpp<0x143>(x);   // row_bcast:31
    return __int_as_float(__builtin_amdgcn_readlane(__float_as_int(x), 63));
}

// Fused kernel:
//   blocks [0, B)      : CTC forward, one 64-lane wave per batch element.
//   blocks [B, B+TRB)  : log + transpose, b-major contiguous 16KB reads.
//
// R8 redesign of the CTC gather path: the LDS staging pipeline (coalesced
// row loads -> 32-VGPR prr ring -> ds_write -> 20 bank-conflicted ds_read
// per group) only existed to transpose coalesced loads into the 20 floats
// a group actually consumes. Replace it with direct scatter gathers:
// SGPR row base (row index is wave-uniform -> SALU address math only) +
// per-lane label voffset, 3 groups of prefetch distance (60 outstanding
// VMEM < vmcnt limit 63) to cover L2/L3/HBM latency. This deletes all LDS
// traffic, all 681K bank conflicts, and ~40 VGPRs of ring pressure (the
// R7 VGPR=132 could not hold the old pipeline's ~180 live values -> AGPR
// spill copies inflated VALU ~2x over source).
// Rescale is software-pipelined: measure (serial DPP tree) after group G,
// apply after G+1 -- the recurrence is linear so the exact power-of-2
// scale commutes; the tree's dependency chain interleaves with the next
// wedge instead of stalling the in-order wave. Apply scales all 17 w's
// (halo included) for cross-lane scale consistency.
__global__
__attribute__((amdgpu_waves_per_eu(1, 1)))
__launch_bounds__(64)
void ctc_fused(
    const float* __restrict__ yp,    // [B,T,C] probabilities
    const int*   __restrict__ yt,    // [B,L]
    const int*   __restrict__ il_,   // [B]
    const int*   __restrict__ ll_,   // [B]
    float* __restrict__ out_log,     // [T,B,C]
    float* __restrict__ out_loss)    // scalar, pre-zeroed; atomic mean
{
    const int lane = threadIdx.x;
    if (blockIdx.x >= B) {
        // ---- transpose + log path: one b, 32 consecutive t-rows per block.
        int id = blockIdx.x - B;     // 0..2047
        int bb = id >> 5;            // batch element
        int ck = id & 31;            // which 32-row chunk of T
        const float4* src = (const float4*)yp + ((size_t)bb * T + ck * 32) * 32;
        float4* o4 = (float4*)out_log;
        #pragma unroll
        for (int k = 0; k < 16; ++k) {
            int o = k * 64 + lane;               // 0..1023 (contiguous read)
            float4 v = src[o];
            int tt = ck * 32 + (o >> 5);
            int c4 = o & 31;
            float4 r;
            r.x = __logf(v.x); r.y = __logf(v.y);
            r.z = __logf(v.z); r.w = __logf(v.w);
            o4[((size_t)tt * B + bb) * 32 + c4] = r;
        }
        return;
    }

    // ---- CTC forward path ----
    const int b = blockIdx.x;

    __shared__ float afin[S];     // final alphas for loss extraction

    int il = il_[b]; il = min(max(il, 1), T);
    int ll = ll_[b]; ll = min(max(ll, 1), L);
    const float* yb = yp + (size_t)b * T * C;   // [T,C] slice for this b

    // Labels. Lane owns states s = 8*lane-8+i in w[i], i in [0,16];
    // persistent alphas in w[8..16] (states 8l..8l+8), w[0..7] is the halo.
    int4 y4  = *(const int4*)(yt + b * L + 4 * lane);
    int  po  = lane ? 4 * lane - 4 : 0;
    int4 py4 = *(const int4*)(yt + b * L + po);              // prev lane's labels
    int  ppw = yt[b * L + (lane >= 2 ? 4 * lane - 5 : 0)];

    int lab[8]   = {py4.x, py4.y, py4.z, py4.w, y4.x, y4.y, y4.z, y4.w};
    int labm1[8] = {ppw,   py4.x, py4.y, py4.z, py4.w, y4.x, y4.y, y4.z};
    float skf[8];
    #pragma unroll
    for (int k = 0; k < 8; ++k)
        skf[k] = ((4 * lane + k >= 5) && (lab[k] != labm1[k])) ? 1.f : 0.f;

    const int c0 = y4.x, c1 = y4.y, c2 = y4.z, c3 = y4.w;  // own columns

    // Opaque zero voffset: keeps the (lane-uniform-address) blank loads on
    // the VECTOR memory path. If they scalarize to s_load, every consume's
    // lgkmcnt(0) would drain the newest prefetches too (SMEM is unordered)
    // and serialize the pipeline.
    int z0;
    asm volatile("v_mov_b32 %0, 0" : "=v"(z0));

    // Gather rings: gv[q][j][*] = own-label probs of ring buffer q, row j;
    // gbv[q][j] = blank prob. Filled by direct global scatter loads.
    float gv[4][4][4], gbv[4][4];

    // Fill ring buffer Q with rows r0..r0+3 (row index wave-uniform ->
    // SALU base + per-lane voffset; rows clamped to T-1, rows >= il are
    // never consumed).
    auto fill = [&](auto Qc, int r0) {
        constexpr int Q = decltype(Qc)::value;
        #pragma unroll
        for (int j = 0; j < 4; ++j) {
            int r = r0 + j; r = r < T ? r : T - 1;
            const float* rb = yb + (size_t)r * C;
            gbv[Q][j]   = rb[z0];
            gv[Q][j][0] = rb[c0];
            gv[Q][j][1] = rb[c1];
            gv[Q][j][2] = rb[c2];
            gv[Q][j][3] = rb[c3];
        }
    };

    float p00 = yb[0];
    float p0l = yb[c0];

    // ---- warm-up: 3 ring buffers ahead (rows 1..12) ----
    fill(IC<0>{}, 1);
    fill(IC<1>{}, 5);
    fill(IC<2>{}, 9);

    float w[17];
    #pragma unroll
    for (int i = 0; i < 17; ++i) w[i] = 0.f;
    if (lane == 0) { w[8] = p00; w[9] = p0l; }   // alpha0: states 0,1

    auto halo = [&]() {       // pure VALU (DPP), no DS
        #pragma unroll
        for (int k = 0; k < 8; ++k) w[k] = shr1(w[8 + k]);
    };
    halo();

    int lsi = 0;           // accumulated log2 scale (exact integer, scalar)
    int t0 = 0;

    // One 4-step group: phase P (compile-time). Consumes ring buffer P,
    // refills buffer (P+3)&3 for group G+3 (3-group prefetch distance).
    auto group = [&](auto Pc) {
        constexpr int P = decltype(Pc)::value;
        constexpr int F = (P + 3) & 3;
        // label-halo for this group's wedge: prev lane's own gathers (DPP).
        float g1[4], g2[4], g3[4];
        #pragma unroll
        for (int j = 0; j < 4; ++j) {
            g1[j] = shr1(gv[P][j][1]);
            g2[j] = shr1(gv[P][j][2]);
            g3[j] = shr1(gv[P][j][3]);
        }
        // wedge: 4 halo-blocked steps, in-place descending.
        #pragma unroll
        for (int j = 0; j < 4; ++j) {
            #pragma unroll
            for (int i = 16; i >= 2 * (j + 1); --i) {
                float acc = w[i] + w[i - 1];
                float g;
                if (i & 1) {
                    const int k = (i - 1) >> 1;
                    acc = fmaf(skf[k], w[i - 2], acc);
                    g = (k >= 4) ? gv[P][j][k - 4]
                                 : (k == 1 ? g1[j] : (k == 2 ? g2[j] : g3[j]));
                } else {
                    g = gbv[P][j];
                }
                w[i] = acc * g;
            }
        }
        // prefetch gathers for group G+3 (rows t0+13..t0+16).
        fill(IC<F>{}, t0 + 13);
        // Pin this group's memory cluster (loads stay here; ALU may move
        // freely across). Keeps the scatter prefetch 3 groups early.
        __builtin_amdgcn_sched_barrier(0x7);
        halo();
        t0 += 4;
    };

    auto maxw = [&]() {
        return fmaxf(fmaxf(fmaxf(w[8], w[9]), fmaxf(w[10], w[11])),
                     fmaxf(fmaxf(w[12], w[13]),
                           fmaxf(fmaxf(w[14], w[15]), w[16])));
    };

    // Pipelined rescale. measure(): local max tree + 6-stage DPP reduce +
    // readlane + scalar exponent math -> pending power-of-2 factor.
    // apply(): 17 exact muls + scale bookkeeping, one group later. The
    // serial DPP chain overlaps the next group's independent wedge VALU.
    int pinv_bits = 127 << 23;   // pending factor, 1.0f
    int psh = 0;                 // pending log2 adjustment
    auto measure = [&]() {
        float mm = wave_max_dpp(maxw());
        int eb = (__float_as_int(mm) >> 23) & 0xff;
        int sh = 350 - eb;
        sh = sh > 254 ? 254 : (sh < 1 ? 1 : sh);
        pinv_bits = sh << 23;
        psh = sh - 127;
    };
    auto apply = [&]() {
        float inv = __int_as_float(pinv_bits);
        #pragma unroll
        for (int i = 0; i < 17; ++i) w[i] *= inv;   // halo too: one scale
        lsi -= psh;
    };
    auto rescale = [&]() { measure(); apply(); };   // serial form for peels

    const int full_end = ((il - 1) >> 2) << 2;

    // Main body: 4 groups (16 steps) per iteration; measure after G1/G3,
    // apply after G2/G0' (1-group delay; exact since scale is power-of-2
    // and the recurrence is linear).
    while (t0 + 16 <= full_end) {
        group(IC<0>{});
        apply();                 // applies prev iteration's G3 measure
        group(IC<1>{});
        measure();
        group(IC<2>{});
        apply();
        group(IC<3>{});
        measure();
    }
    apply();                     // drain pending scale

    // Peeled groups (0..3). Loop exits with t0 % 16 == 0, so phases 0,1,2.
    if (t0 + 4 <= full_end) { group(IC<0>{}); rescale(); }
    if (t0 + 4 <= full_end) { group(IC<1>{}); rescale(); }
    if (t0 + 4 <= full_end) { group(IC<2>{}); }

    // Tail: rows full_end+1 .. il-1 (0..3 steps) from gv[(full_end/4)&3].
    const int ph = (full_end >> 2) & 3;
    float tg[3][4], tb[3];
    switch (ph) {
    case 0:
        #pragma unroll
        for (int j = 0; j < 3; ++j) { tb[j]=gbv[0][j]; tg[j][0]=gv[0][j][0]; tg[j][1]=gv[0][j][1]; tg[j][2]=gv[0][j][2]; tg[j][3]=gv[0][j][3]; }
        break;
    case 1:
        #pragma unroll
        for (int j = 0; j < 3; ++j) { tb[j]=gbv[1][j]; tg[j][0]=gv[1][j][0]; tg[j][1]=gv[1][j][1]; tg[j][2]=gv[1][j][2]; tg[j][3]=gv[1][j][3]; }
        break;
    case 2:
        #pragma unroll
        for (int j = 0; j < 3; ++j) { tb[j]=gbv[2][j]; tg[j][0]=gv[2][j][0]; tg[j][1]=gv[2][j][1]; tg[j][2]=gv[2][j][2]; tg[j][3]=gv[2][j][3]; }
        break;
    default:
        #pragma unroll
        for (int j = 0; j < 3; ++j) { tb[j]=gbv[3][j]; tg[j][0]=gv[3][j][0]; tg[j][1]=gv[3][j][1]; tg[j][2]=gv[3][j][2]; tg[j][3]=gv[3][j][3]; }
        break;
    }
    #pragma unroll
    for (int j = 0; j < 3; ++j) {
        int r = full_end + 1 + j;
        if (r < il) {   // uniform branch (il, r wave-uniform)
            float hh = shr1(w[15]);
            float gb = tb[j];
            float n8  = (w[8] + hh) * gb;
            float n9  = fmaf(skf[4], hh,    w[9]  + w[8])  * tg[j][0];
            float n10 = (w[10] + w[9])  * gb;
            float n11 = fmaf(skf[5], w[9],  w[11] + w[10]) * tg[j][1];
            float n12 = (w[12] + w[11]) * gb;
            float n13 = fmaf(skf[6], w[11], w[13] + w[12]) * tg[j][2];
            float n14 = (w[14] + w[13]) * gb;
            float n15 = fmaf(skf[7], w[13], w[15] + w[14]) * tg[j][3];
            float n16 = (w[16] + w[15]) * gb;
            w[8] = n8;  w[9] = n9;  w[10] = n10; w[11] = n11; w[12] = n12;
            w[13] = n13; w[14] = n14; w[15] = n15; w[16] = n16;
        }
    }

    // Loss: -ln(alpha[2ll-1] + alpha[2ll]) with accumulated scale.
    #pragma unroll
    for (int k = 0; k < 8; ++k) afin[8 * lane + k] = w[8 + k];
    if (lane == 63) afin[512] = w[16];
    __syncthreads();
    if (lane == 0) {
        float e1 = afin[2 * ll - 1];
        float e2 = afin[2 * ll];
        float sum = fmaxf(e1 + e2, 1e-37f);
        float loss = -(__log2f(sum) + (float)lsi) * 0.6931471805599453f;  // nats
        atomicAdd(out_loss, loss * (1.0f / (float)B));
    }
}

extern "C" void kernel_launch(void* const* d_in, const int* in_sizes, int n_in,
                              void* d_out, int out_size, void* d_ws, size_t ws_size,
                              hipStream_t stream) {
    const int*   y_true = (const int*)d_in[0];
    const float* y_pred = (const float*)d_in[1];
    const int*   in_len = (const int*)d_in[2];
    const int*   lb_len = (const int*)d_in[3];

    float* out_log  = (float*)d_out;                      // [T,B,C]
    float* out_loss = (float*)d_out + (size_t)T * B * C;  // scalar

    hipMemsetAsync(out_loss, 0, sizeof(float), stream);
    ctc_fused<<<B + TRB, 64, 0, stream>>>(y_pred, y_true, in_len, lb_len,
                                          out_log, out_loss);
}

// Round 3
// 177.397 us; speedup vs baseline: 1.0749x; 1.0749x over previous
//
#include <hip/hip_runtime.h>
#include <math.h>

// Problem constants (from reference setup_inputs)
constexpr int B = 64;
constexpr int T = 1024;
constexpr int C = 128;
constexpr int L = 256;
constexpr int S = 2 * L + 1;     // 513 extended states
constexpr int TRB = 2048;        // transpose blocks (blockIdx >= B)

template <int N> struct IC { static constexpr int value = N; };

// shfl_up by 1 lane as pure VALU DPP (wave_shr:1), bound_ctrl=1 so lane 0
// reads 0 (the CTC halo boundary) without a v_mov-zero of the old operand.
__device__ __forceinline__ float shr1(float x) {
#if __has_builtin(__builtin_amdgcn_mov_dpp)
    return __int_as_float(__builtin_amdgcn_mov_dpp(
        __float_as_int(x), 0x138 /*WAVE_SHR1*/, 0xf, 0xf, true));
#else
    return __int_as_float(__builtin_amdgcn_update_dpp(
        0, __float_as_int(x), 0x138, 0xf, 0xf, true));
#endif
}

// One DPP max-combine stage. bound_ctrl=1: source-less lanes read 0,
// harmless for a max of non-negative alphas.
template <int CTRL>
__device__ __forceinline__ float maxdpp(float x) {
#if __has_builtin(__builtin_amdgcn_mov_dpp)
    float t = __int_as_float(__builtin_amdgcn_mov_dpp(
        __float_as_int(x), CTRL, 0xf, 0xf, true));
#else
    float t = __int_as_float(__builtin_amdgcn_update_dpp(
        0, __float_as_int(x), CTRL, 0xf, 0xf, true));
#endif
    return fmaxf(x, t);
}

// Wave64 max-reduce -> wave-uniform value (readlane 63).
__device__ __forceinline__ float wave_max_dpp(float x) {
    x = maxdpp<0x111>(x);   // row_shr:1
    x = maxdpp<0x112>(x);   // row_shr:2
    x = maxdpp<0x114>(x);   // row_shr:4
    x = maxdpp<0x118>(x);   // row_shr:8
    x = maxdpp<0x142>(x);   // row_bcast:15
    x = maxdpp<0x143>(x);   // row_bcast:31
    return __int_as_float(__builtin_amdgcn_readlane(__float_as_int(x), 63));
}

// Fused kernel:
//   blocks [0, B)      : CTC forward, one 64-lane wave per batch element.
//   blocks [B, B+TRB)  : log + transpose, b-major contiguous 16KB reads.
//
// R9: register-budget round. R8 (direct global gathers, no LDS) proved
// bank conflicts / LDS were NOT the bottleneck (681K -> 1K conflicts,
// time unchanged at ~1070 cyc/group). Remaining theory: live set ~140
// (4-buffer gather ring = 80 regs) > VGPR_Count=132 -> AGPR-spill /
// remat VALU traffic ~doubles the issue count per group. Fix: prefetch
// distance 3 -> 2 (ring 4 -> 3 buffers, 60 regs). Live set ~112 < 132.
// Distance 2 still leaves a full group (~700+ cyc) of slack over the
// L2/L3-resident gather latency (~200-400 cyc), so no new exposure.
__global__
__attribute__((amdgpu_waves_per_eu(1, 1)))
__launch_bounds__(64)
void ctc_fused(
    const float* __restrict__ yp,    // [B,T,C] probabilities
    const int*   __restrict__ yt,    // [B,L]
    const int*   __restrict__ il_,   // [B]
    const int*   __restrict__ ll_,   // [B]
    float* __restrict__ out_log,     // [T,B,C]
    float* __restrict__ out_loss)    // scalar, pre-zeroed; atomic mean
{
    const int lane = threadIdx.x;
    if (blockIdx.x >= B) {
        // ---- transpose + log path: one b, 32 consecutive t-rows per block.
        int id = blockIdx.x - B;     // 0..2047
        int bb = id >> 5;            // batch element
        int ck = id & 31;            // which 32-row chunk of T
        const float4* src = (const float4*)yp + ((size_t)bb * T + ck * 32) * 32;
        float4* o4 = (float4*)out_log;
        #pragma unroll
        for (int k = 0; k < 16; ++k) {
            int o = k * 64 + lane;               // 0..1023 (contiguous read)
            float4 v = src[o];
            int tt = ck * 32 + (o >> 5);
            int c4 = o & 31;
            float4 r;
            r.x = __logf(v.x); r.y = __logf(v.y);
            r.z = __logf(v.z); r.w = __logf(v.w);
            o4[((size_t)tt * B + bb) * 32 + c4] = r;
        }
        return;
    }

    // ---- CTC forward path ----
    const int b = blockIdx.x;

    __shared__ float afin[S];     // final alphas for loss extraction

    int il = il_[b]; il = min(max(il, 1), T);
    int ll = ll_[b]; ll = min(max(ll, 1), L);
    const float* yb = yp + (size_t)b * T * C;   // [T,C] slice for this b

    // Labels. Lane owns states s = 8*lane-8+i in w[i], i in [0,16];
    // persistent alphas in w[8..16] (states 8l..8l+8), w[0..7] is the halo.
    int4 y4  = *(const int4*)(yt + b * L + 4 * lane);
    int  po  = lane ? 4 * lane - 4 : 0;
    int4 py4 = *(const int4*)(yt + b * L + po);              // prev lane's labels
    int  ppw = yt[b * L + (lane >= 2 ? 4 * lane - 5 : 0)];

    int lab[8]   = {py4.x, py4.y, py4.z, py4.w, y4.x, y4.y, y4.z, y4.w};
    int labm1[8] = {ppw,   py4.x, py4.y, py4.z, py4.w, y4.x, y4.y, y4.z};
    float skf[8];
    #pragma unroll
    for (int k = 0; k < 8; ++k)
        skf[k] = ((4 * lane + k >= 5) && (lab[k] != labm1[k])) ? 1.f : 0.f;

    const int c0 = y4.x, c1 = y4.y, c2 = y4.z, c3 = y4.w;  // own columns

    // Opaque zero voffset: keeps the (lane-uniform-address) blank loads on
    // the VECTOR memory path so one vmcnt discipline covers everything.
    int z0;
    asm volatile("v_mov_b32 %0, 0" : "=v"(z0));

    // Gather ring: 3 buffers, distance-2 prefetch.
    // gv[q][j][*] = own-label probs of ring buffer q, row j; gbv = blank.
    float gv[3][4][4], gbv[3][4];

    // Fill ring buffer Q with rows r0..r0+3 (row index wave-uniform ->
    // SALU base + per-lane voffset; rows clamped to T-1, rows >= il are
    // never consumed).
    auto fill = [&](auto Qc, int r0) {
        constexpr int Q = decltype(Qc)::value;
        #pragma unroll
        for (int j = 0; j < 4; ++j) {
            int r = r0 + j; r = r < T ? r : T - 1;
            const float* rb = yb + (size_t)r * C;
            gbv[Q][j]   = rb[z0];
            gv[Q][j][0] = rb[c0];
            gv[Q][j][1] = rb[c1];
            gv[Q][j][2] = rb[c2];
            gv[Q][j][3] = rb[c3];
        }
    };

    float p00 = yb[0];
    float p0l = yb[c0];

    // ---- warm-up: 2 ring buffers ahead (rows 1..8) ----
    fill(IC<0>{}, 1);
    fill(IC<1>{}, 5);

    float w[17];
    #pragma unroll
    for (int i = 0; i < 17; ++i) w[i] = 0.f;
    if (lane == 0) { w[8] = p00; w[9] = p0l; }   // alpha0: states 0,1

    auto halo = [&]() {       // pure VALU (DPP), no DS
        #pragma unroll
        for (int k = 0; k < 8; ++k) w[k] = shr1(w[8 + k]);
    };
    halo();

    int lsi = 0;           // accumulated log2 scale (exact integer, scalar)
    int t0 = 0;

    // One 4-step group: phase P in {0,1,2} (compile-time). Consumes ring
    // buffer P, refills buffer (P+2)%3 for group G+2 (distance-2 prefetch:
    // a full group ~700+ cyc of slack before consumption).
    auto group = [&](auto Pc) {
        constexpr int P = decltype(Pc)::value;
        constexpr int F = (P + 2) % 3;
        // label-halo for this group's wedge: prev lane's own gathers (DPP).
        float g1[4], g2[4], g3[4];
        #pragma unroll
        for (int j = 0; j < 4; ++j) {
            g1[j] = shr1(gv[P][j][1]);
            g2[j] = shr1(gv[P][j][2]);
            g3[j] = shr1(gv[P][j][3]);
        }
        // wedge: 4 halo-blocked steps, in-place descending.
        #pragma unroll
        for (int j = 0; j < 4; ++j) {
            #pragma unroll
            for (int i = 16; i >= 2 * (j + 1); --i) {
                float acc = w[i] + w[i - 1];
                float g;
                if (i & 1) {
                    const int k = (i - 1) >> 1;
                    acc = fmaf(skf[k], w[i - 2], acc);
                    g = (k >= 4) ? gv[P][j][k - 4]
                                 : (k == 1 ? g1[j] : (k == 2 ? g2[j] : g3[j]));
                } else {
                    g = gbv[P][j];
                }
                w[i] = acc * g;
            }
        }
        // prefetch gathers for group G+2 (rows t0+9..t0+12).
        fill(IC<F>{}, t0 + 9);
        // Pin this group's memory cluster (loads stay here; ALU may move
        // freely across). Keeps the scatter prefetch 2 groups early.
        __builtin_amdgcn_sched_barrier(0x7);
        halo();
        t0 += 4;
    };

    auto maxw = [&]() {
        return fmaxf(fmaxf(fmaxf(w[8], w[9]), fmaxf(w[10], w[11])),
                     fmaxf(fmaxf(w[12], w[13]),
                           fmaxf(fmaxf(w[14], w[15]), w[16])));
    };

    // Pipelined rescale: measure (serial DPP tree) after group G, apply
    // (17 exact power-of-2 muls) after G+1; commutes with the linear
    // recurrence, and the DPP chain overlaps the next wedge's VALU.
    int pinv_bits = 127 << 23;   // pending factor, 1.0f
    int psh = 0;                 // pending log2 adjustment
    auto measure = [&]() {
        float mm = wave_max_dpp(maxw());
        int eb = (__float_as_int(mm) >> 23) & 0xff;
        int sh = 350 - eb;
        sh = sh > 254 ? 254 : (sh < 1 ? 1 : sh);
        pinv_bits = sh << 23;
        psh = sh - 127;
    };
    auto apply = [&]() {
        float inv = __int_as_float(pinv_bits);
        #pragma unroll
        for (int i = 0; i < 17; ++i) w[i] *= inv;   // halo too: one scale
        lsi -= psh;
    };
    auto rescale = [&]() { measure(); apply(); };   // serial form for peels

    const int full_end = ((il - 1) >> 2) << 2;

    // Main body: 6 groups (24 steps) per iteration -- LCM of the 3-phase
    // ring and the 2-group rescale cadence. apply after even groups,
    // measure after odd groups (1-group delay; exact, power-of-2 scale).
    while (t0 + 24 <= full_end) {
        group(IC<0>{});
        apply();
        group(IC<1>{});
        measure();
        group(IC<2>{});
        apply();
        group(IC<0>{});
        measure();
        group(IC<1>{});
        apply();
        group(IC<2>{});
        measure();
    }
    apply();                     // drain pending scale

    // Peeled groups (0..5 remain; phases continue 0,1,2,0,1).
    if (t0 + 4 <= full_end) { group(IC<0>{}); rescale(); }
    if (t0 + 4 <= full_end) { group(IC<1>{}); rescale(); }
    if (t0 + 4 <= full_end) { group(IC<2>{}); rescale(); }
    if (t0 + 4 <= full_end) { group(IC<0>{}); rescale(); }
    if (t0 + 4 <= full_end) { group(IC<1>{}); }

    // Tail: rows full_end+1 .. il-1 (0..3 steps) from buffer (full_end/4)%3.
    const int ph = (full_end >> 2) % 3;
    float tg[3][4], tb[3];
    switch (ph) {
    case 0:
        #pragma unroll
        for (int j = 0; j < 3; ++j) { tb[j]=gbv[0][j]; tg[j][0]=gv[0][j][0]; tg[j][1]=gv[0][j][1]; tg[j][2]=gv[0][j][2]; tg[j][3]=gv[0][j][3]; }
        break;
    case 1:
        #pragma unroll
        for (int j = 0; j < 3; ++j) { tb[j]=gbv[1][j]; tg[j][0]=gv[1][j][0]; tg[j][1]=gv[1][j][1]; tg[j][2]=gv[1][j][2]; tg[j][3]=gv[1][j][3]; }
        break;
    default:
        #pragma unroll
        for (int j = 0; j < 3; ++j) { tb[j]=gbv[2][j]; tg[j][0]=gv[2][j][0]; tg[j][1]=gv[2][j][1]; tg[j][2]=gv[2][j][2]; tg[j][3]=gv[2][j][3]; }
        break;
    }
    #pragma unroll
    for (int j = 0; j < 3; ++j) {
        int r = full_end + 1 + j;
        if (r < il) {   // uniform branch (il, r wave-uniform)
            float hh = shr1(w[15]);
            float gb = tb[j];
            float n8  = (w[8] + hh) * gb;
            float n9  = fmaf(skf[4], hh,    w[9]  + w[8])  * tg[j][0];
            float n10 = (w[10] + w[9])  * gb;
            float n11 = fmaf(skf[5], w[9],  w[11] + w[10]) * tg[j][1];
            float n12 = (w[12] + w[11]) * gb;
            float n13 = fmaf(skf[6], w[11], w[13] + w[12]) * tg[j][2];
            float n14 = (w[14] + w[13]) * gb;
            float n15 = fmaf(skf[7], w[13], w[15] + w[14]) * tg[j][3];
            float n16 = (w[16] + w[15]) * gb;
            w[8] = n8;  w[9] = n9;  w[10] = n10; w[11] = n11; w[12] = n12;
            w[13] = n13; w[14] = n14; w[15] = n15; w[16] = n16;
        }
    }

    // Loss: -ln(alpha[2ll-1] + alpha[2ll]) with accumulated scale.
    #pragma unroll
    for (int k = 0; k < 8; ++k) afin[8 * lane + k] = w[8 + k];
    if (lane == 63) afin[512] = w[16];
    __syncthreads();
    if (lane == 0) {
        float e1 = afin[2 * ll - 1];
        float e2 = afin[2 * ll];
        float sum = fmaxf(e1 + e2, 1e-37f);
        float loss = -(__log2f(sum) + (float)lsi) * 0.6931471805599453f;  // nats
        atomicAdd(out_loss, loss * (1.0f / (float)B));
    }
}

extern "C" void kernel_launch(void* const* d_in, const int* in_sizes, int n_in,
                              void* d_out, int out_size, void* d_ws, size_t ws_size,
                              hipStream_t stream) {
    const int*   y_true = (const int*)d_in[0];
    const float* y_pred = (const float*)d_in[1];
    const int*   in_len = (const int*)d_in[2];
    const int*   lb_len = (const int*)d_in[3];

    float* out_log  = (float*)d_out;                      // [T,B,C]
    float* out_loss = (float*)d_out + (size_t)T * B * C;  // scalar

    hipMemsetAsync(out_loss, 0, sizeof(float), stream);
    ctc_fused<<<B + TRB, 64, 0, stream>>>(y_pred, y_true, in_len, lb_len,
                                          out_log, out_loss);
}

// Round 4
// 171.180 us; speedup vs baseline: 1.1139x; 1.0363x over previous
//
#include <hip/hip_runtime.h>
#include <math.h>

// Problem constants (from reference setup_inputs)
constexpr int B = 64;
constexpr int T = 1024;
constexpr int C = 128;
constexpr int L = 256;
constexpr int S = 2 * L + 1;     // 513 extended states
constexpr int TRB = 2048;        // transpose blocks (blockIdx >= B)

template <int N> struct IC { static constexpr int value = N; };

// shfl_up by 1 lane as pure VALU DPP (wave_shr:1), bound_ctrl=1 so lane 0
// reads 0 (the CTC halo boundary) without a v_mov-zero of the old operand.
__device__ __forceinline__ float shr1(float x) {
#if __has_builtin(__builtin_amdgcn_mov_dpp)
    return __int_as_float(__builtin_amdgcn_mov_dpp(
        __float_as_int(x), 0x138 /*WAVE_SHR1*/, 0xf, 0xf, true));
#else
    return __int_as_float(__builtin_amdgcn_update_dpp(
        0, __float_as_int(x), 0x138, 0xf, 0xf, true));
#endif
}

// One DPP max-combine stage. bound_ctrl=1: source-less lanes read 0,
// harmless for a max of non-negative alphas.
template <int CTRL>
__device__ __forceinline__ float maxdpp(float x) {
#if __has_builtin(__builtin_amdgcn_mov_dpp)
    float t = __int_as_float(__builtin_amdgcn_mov_dpp(
        __float_as_int(x), CTRL, 0xf, 0xf, true));
#else
    float t = __int_as_float(__builtin_amdgcn_update_dpp(
        0, __float_as_int(x), CTRL, 0xf, 0xf, true));
#endif
    return fmaxf(x, t);
}

// Wave64 max-reduce -> wave-uniform value (readlane 63).
__device__ __forceinline__ float wave_max_dpp(float x) {
    x = maxdpp<0x111>(x);   // row_shr:1
    x = maxdpp<0x112>(x);   // row_shr:2
    x = maxdpp<0x114>(x);   // row_shr:4
    x = maxdpp<0x118>(x);   // row_bcast:15 comes later; shr:8 here
    x = maxdpp<0x142>(x);   // row_bcast:15
    x = maxdpp<0x143>(x);   // row_bcast:31
    return __int_as_float(__builtin_amdgcn_readlane(__float_as_int(x), 63));
}

// Fused kernel:
//   blocks [0, B)      : CTC forward, one 64-lane wave per batch element.
//   blocks [B, B+TRB)  : log + transpose, b-major contiguous 16KB reads.
//
// R10: instruction-diet round. VALUBusy normalization (4.9% device-wide /
// 64 active waves) showed ~800 VALU-busy cycles of the ~1070-cycle group:
// the wave is VALU-ISSUE-bound, and three different memory pipelines
// (R6/R8/R9) changing nothing confirms memory is off the critical path.
// The halo-blocked wedge (48 updates/group incl. 12 redundant halo-region
// updates + 12 label-halo DPPs + 8-DPP halo refresh + 17-mul rescale)
// was built for the era of ~120cyc ds_swizzle halos. With 1-instr DPP
// shr1, plain per-step updates are strictly cheaper: 1 DPP + 22 VALU per
// step, no halo state at all, 9-mul rescale apply. ~28% fewer source
// instructions per group.
__global__
__attribute__((amdgpu_waves_per_eu(1, 1)))
__launch_bounds__(64)
void ctc_fused(
    const float* __restrict__ yp,    // [B,T,C] probabilities
    const int*   __restrict__ yt,    // [B,L]
    const int*   __restrict__ il_,   // [B]
    const int*   __restrict__ ll_,   // [B]
    float* __restrict__ out_log,     // [T,B,C]
    float* __restrict__ out_loss)    // scalar, pre-zeroed; atomic mean
{
    const int lane = threadIdx.x;
    if (blockIdx.x >= B) {
        // ---- transpose + log path: one b, 32 consecutive t-rows per block.
        int id = blockIdx.x - B;     // 0..2047
        int bb = id >> 5;            // batch element
        int ck = id & 31;            // which 32-row chunk of T
        const float4* src = (const float4*)yp + ((size_t)bb * T + ck * 32) * 32;
        float4* o4 = (float4*)out_log;
        #pragma unroll
        for (int k = 0; k < 16; ++k) {
            int o = k * 64 + lane;               // 0..1023 (contiguous read)
            float4 v = src[o];
            int tt = ck * 32 + (o >> 5);
            int c4 = o & 31;
            float4 r;
            r.x = __logf(v.x); r.y = __logf(v.y);
            r.z = __logf(v.z); r.w = __logf(v.w);
            o4[((size_t)tt * B + bb) * 32 + c4] = r;
        }
        return;
    }

    // ---- CTC forward path ----
    const int b = blockIdx.x;

    __shared__ float afin[S];     // final alphas for loss extraction

    int il = il_[b]; il = min(max(il, 1), T);
    int ll = ll_[b]; ll = min(max(ll, 1), L);
    const float* yb = yp + (size_t)b * T * C;   // [T,C] slice for this b

    // Labels. Lane owns states 8*lane+k in a[k], k in [0,8] (a[8] is state
    // 8*lane+8, duplicating the next lane's a[0]; needed by lane 63 for
    // state 512). Odd states 8l+1/3/5/7 have labels y4.x/y/z/w.
    int4 y4 = *(const int4*)(yt + b * L + 4 * lane);
    int  pw = yt[b * L + (lane ? 4 * lane - 1 : 0)];  // prev label (lane-1's w)

    // skip-transition gates for the 4 odd states this lane owns.
    float skf4 = (lane && (y4.x != pw))   ? 1.f : 0.f;  // state 8l+1 (s>=3)
    float skf5 = (y4.y != y4.x) ? 1.f : 0.f;            // state 8l+3
    float skf6 = (y4.z != y4.y) ? 1.f : 0.f;            // state 8l+5
    float skf7 = (y4.w != y4.z) ? 1.f : 0.f;            // state 8l+7

    const int c0 = y4.x, c1 = y4.y, c2 = y4.z, c3 = y4.w;  // own columns

    // Opaque zero voffset: keeps the (lane-uniform-address) blank loads on
    // the VECTOR memory path so one vmcnt discipline covers everything.
    int z0;
    asm volatile("v_mov_b32 %0, 0" : "=v"(z0));

    // Gather ring: 3 buffers, distance-2 prefetch.
    // gv[q][j][*] = own-label probs of ring buffer q, row j; gbv = blank.
    float gv[3][4][4], gbv[3][4];

    // Fill ring buffer Q with rows r0..r0+3. Single clamp r0 <= T-4 keeps
    // all 4 rows in-bounds with one SGPR base + immediate offsets (the
    // clamp only binds for fills whose rows are never consumed as groups;
    // the tail compensates with a +1 slot shift, see tsh below).
    auto fill = [&](auto Qc, int r0) {
        constexpr int Q = decltype(Qc)::value;
        int r = r0 < T - 4 ? r0 : T - 4;
        const float* rb = yb + (size_t)r * C;
        #pragma unroll
        for (int j = 0; j < 4; ++j) {
            gbv[Q][j]   = rb[j * C + z0];
            gv[Q][j][0] = rb[j * C + c0];
            gv[Q][j][1] = rb[j * C + c1];
            gv[Q][j][2] = rb[j * C + c2];
            gv[Q][j][3] = rb[j * C + c3];
        }
    };

    float p00 = yb[0];
    float p0l = yb[c0];

    // ---- warm-up: 2 ring buffers ahead (rows 1..8) ----
    fill(IC<0>{}, 1);
    fill(IC<1>{}, 5);

    float a[9];
    #pragma unroll
    for (int i = 0; i < 9; ++i) a[i] = 0.f;
    if (lane == 0) { a[0] = p00; a[1] = p0l; }   // alpha0: states 0,1

    int lsi = 0;           // accumulated log2 scale (exact integer, scalar)
    int t0 = 0;

    // One time step. hh = alpha[8l-1] (prev lane's a[7]) is the ONLY
    // cross-lane input; everything else is lane-local. 1 DPP + 22 VALU.
    auto step = [&](float gb, float g0, float g1, float g2, float g3) {
        float hh = shr1(a[7]);
        float n0 = (a[0] + hh)                      * gb;
        float n1 = fmaf(skf4, hh,   a[1] + a[0])    * g0;
        float n2 = (a[2] + a[1])                    * gb;
        float n3 = fmaf(skf5, a[1], a[3] + a[2])    * g1;
        float n4 = (a[4] + a[3])                    * gb;
        float n5 = fmaf(skf6, a[3], a[5] + a[4])    * g2;
        float n6 = (a[6] + a[5])                    * gb;
        float n7 = fmaf(skf7, a[5], a[7] + a[6])    * g3;
        float n8 = (a[8] + a[7])                    * gb;
        a[0] = n0; a[1] = n1; a[2] = n2; a[3] = n3; a[4] = n4;
        a[5] = n5; a[6] = n6; a[7] = n7; a[8] = n8;
    };

    // One 4-step group: phase P in {0,1,2}. Consumes ring buffer P,
    // refills buffer (P+2)%3 for group G+2 (distance-2 prefetch).
    auto group = [&](auto Pc) {
        constexpr int P = decltype(Pc)::value;
        constexpr int F = (P + 2) % 3;
        #pragma unroll
        for (int j = 0; j < 4; ++j)
            step(gbv[P][j], gv[P][j][0], gv[P][j][1], gv[P][j][2], gv[P][j][3]);
        fill(IC<F>{}, t0 + 9);
        // Pin this group's loads here; ALU may move freely across.
        __builtin_amdgcn_sched_barrier(0x7);
        t0 += 4;
    };

    // max over the 9 owned states; nested fmaxf triplets fuse to v_max3.
    auto maxw = [&]() {
        float m0 = fmaxf(fmaxf(a[0], a[1]), a[2]);
        float m1 = fmaxf(fmaxf(a[3], a[4]), a[5]);
        float m2 = fmaxf(fmaxf(a[6], a[7]), a[8]);
        return fmaxf(fmaxf(m0, m1), m2);
    };

    // Pipelined rescale: measure (serial DPP tree) after group G, apply
    // (9 exact power-of-2 muls) after G+1; commutes with the linear
    // recurrence, and the DPP chain overlaps the next group's VALU.
    int pinv_bits = 127 << 23;   // pending factor, 1.0f
    int psh = 0;                 // pending log2 adjustment
    auto measure = [&]() {
        float mm = wave_max_dpp(maxw());
        int eb = (__float_as_int(mm) >> 23) & 0xff;
        int sh = 350 - eb;
        sh = sh > 254 ? 254 : (sh < 1 ? 1 : sh);
        pinv_bits = sh << 23;
        psh = sh - 127;
    };
    auto apply = [&]() {
        float inv = __int_as_float(pinv_bits);
        #pragma unroll
        for (int i = 0; i < 9; ++i) a[i] *= inv;
        lsi -= psh;
    };
    auto rescale = [&]() { measure(); apply(); };   // serial form for peels

    const int full_end = ((il - 1) >> 2) << 2;

    // Main body: 6 groups (24 steps) per iteration -- LCM of the 3-phase
    // ring and the 2-group rescale cadence. apply after even groups,
    // measure after odd groups (1-group delay; exact, power-of-2 scale).
    while (t0 + 24 <= full_end) {
        group(IC<0>{});
        apply();
        group(IC<1>{});
        measure();
        group(IC<2>{});
        apply();
        group(IC<0>{});
        measure();
        group(IC<1>{});
        apply();
        group(IC<2>{});
        measure();
    }
    apply();                     // drain pending scale

    // Peeled groups (0..5 remain; phases continue 0,1,2,0,1).
    if (t0 + 4 <= full_end) { group(IC<0>{}); rescale(); }
    if (t0 + 4 <= full_end) { group(IC<1>{}); rescale(); }
    if (t0 + 4 <= full_end) { group(IC<2>{}); rescale(); }
    if (t0 + 4 <= full_end) { group(IC<0>{}); rescale(); }
    if (t0 + 4 <= full_end) { group(IC<1>{}); }

    // Tail: rows full_end+1 .. il-1 (0..3 steps) from buffer (full_end/4)%3.
    // If the fill clamp bound (il >= T-3), rows sit one slot higher.
    const int ph  = (full_end >> 2) % 3;
    const int tsh = (full_end + 1 > T - 4) ? 1 : 0;
    float tg[3][4], tb[3];
    switch (ph) {
    case 0:
        #pragma unroll
        for (int j = 0; j < 3; ++j) { int s_ = j + tsh; tb[j]=gbv[0][s_]; tg[j][0]=gv[0][s_][0]; tg[j][1]=gv[0][s_][1]; tg[j][2]=gv[0][s_][2]; tg[j][3]=gv[0][s_][3]; }
        break;
    case 1:
        #pragma unroll
        for (int j = 0; j < 3; ++j) { int s_ = j + tsh; tb[j]=gbv[1][s_]; tg[j][0]=gv[1][s_][0]; tg[j][1]=gv[1][s_][1]; tg[j][2]=gv[1][s_][2]; tg[j][3]=gv[1][s_][3]; }
        break;
    default:
        #pragma unroll
        for (int j = 0; j < 3; ++j) { int s_ = j + tsh; tb[j]=gbv[2][s_]; tg[j][0]=gv[2][s_][0]; tg[j][1]=gv[2][s_][1]; tg[j][2]=gv[2][s_][2]; tg[j][3]=gv[2][s_][3]; }
        break;
    }
    #pragma unroll
    for (int j = 0; j < 3; ++j) {
        int r = full_end + 1 + j;
        if (r < il)   // uniform branch (il, r wave-uniform)
            step(tb[j], tg[j][0], tg[j][1], tg[j][2], tg[j][3]);
    }

    // Loss: -ln(alpha[2ll-1] + alpha[2ll]) with accumulated scale.
    #pragma unroll
    for (int k = 0; k < 8; ++k) afin[8 * lane + k] = a[k];
    if (lane == 63) afin[512] = a[8];
    __syncthreads();
    if (lane == 0) {
        float e1 = afin[2 * ll - 1];
        float e2 = afin[2 * ll];
        float sum = fmaxf(e1 + e2, 1e-37f);
        float loss = -(__log2f(sum) + (float)lsi) * 0.6931471805599453f;  // nats
        atomicAdd(out_loss, loss * (1.0f / (float)B));
    }
}

extern "C" void kernel_launch(void* const* d_in, const int* in_sizes, int n_in,
                              void* d_out, int out_size, void* d_ws, size_t ws_size,
                              hipStream_t stream) {
    const int*   y_true = (const int*)d_in[0];
    const float* y_pred = (const float*)d_in[1];
    const int*   in_len = (const int*)d_in[2];
    const int*   lb_len = (const int*)d_in[3];

    float* out_log  = (float*)d_out;                      // [T,B,C]
    float* out_loss = (float*)d_out + (size_t)T * B * C;  // scalar

    hipMemsetAsync(out_loss, 0, sizeof(float), stream);
    ctc_fused<<<B + TRB, 64, 0, stream>>>(y_pred, y_true, in_len, lb_len,
                                          out_log, out_loss);
}